// Round 2
// baseline (250.440 us; speedup 1.0000x reference)
//
#include <hip/hip_runtime.h>
#include <hip/hip_bf16.h>

#define D 128
#define CAT 640
#define KS1 20       // 640/32 k-steps for GEMM1
#define KS2 4        // 128/32 k-steps for GEMM2
#define W1F_ELEMS 81920   // 20*8*64*8
#define W2F_ELEMS 16384   // 4*8*64*8

typedef __attribute__((ext_vector_type(8))) short bf16x8;
typedef __attribute__((ext_vector_type(4))) float f32x4;

static __device__ __forceinline__ unsigned short f32_to_bf16(float f) {
    unsigned u = __float_as_uint(f);
    unsigned r = u + 0x7FFFu + ((u >> 16) & 1u);   // RNE
    return (unsigned short)(r >> 16);
}

// Pack W1 [128][640] and W2 [128][128] (fp32, row-major, torch Linear [out,in])
// into MFMA B-operand fragment order:
//   frag element (ks, j16, lane, e) = W[o = j16*16 + (lane&15)][k = ks*32 + (lane>>4)*8 + e]
__global__ void prep_frags(const float* __restrict__ W1, const float* __restrict__ W2,
                           unsigned short* __restrict__ W1f, unsigned short* __restrict__ W2f) {
    int f = blockIdx.x * 256 + threadIdx.x;
    if (f < W1F_ELEMS) {
        int e = f & 7, l = (f >> 3) & 63, j16 = (f >> 9) & 7, ks = f >> 12;
        int o = j16 * 16 + (l & 15);
        int k = ks * 32 + ((l >> 4) << 3) + e;
        W1f[f] = f32_to_bf16(W1[o * CAT + k]);
    } else if (f < W1F_ELEMS + W2F_ELEMS) {
        int f2 = f - W1F_ELEMS;
        int e = f2 & 7, l = (f2 >> 3) & 63, j16 = (f2 >> 9) & 7, ks = f2 >> 12;
        int o = j16 * 16 + (l & 15);
        int k = ks * 32 + ((l >> 4) << 3) + e;
        W2f[f2] = f32_to_bf16(W2[o * D + k]);
    }
}

// One wave = 16 batch rows x all 128 output features.
// A-fragments gathered DIRECTLY global->reg in MFMA order (no LDS staging,
// no gather phase): lane l reads batch row (l&15), k-chunk (l>>4)*8.
// Each A element fetched exactly once from HBM. Only LDS use: per-wave 4KB
// h-transpose buffer between GEMM1 and GEMM2 (XOR-swizzled, G4).
__global__ __launch_bounds__(256) void rowmlp_kernel(
    const float* __restrict__ x_rows, const int* __restrict__ seeds,
    const unsigned short* __restrict__ W1f, const float* __restrict__ b1,
    const unsigned short* __restrict__ W2f, const float* __restrict__ b2,
    float* __restrict__ out, int Nrows)
{
    __shared__ __align__(16) unsigned short Hbuf[4][16 * D];  // 16 KB

    const int tid = threadIdx.x;
    const int blk = blockIdx.x;
    const int g   = tid >> 6;    // wave id 0..3: rows blk*64 + g*16 ..
    const int l   = tid & 63;
    const int l15 = l & 15;
    const int lhi = l >> 4;

    // clipped neighbor-row byte offsets for this lane's batch row (l&15)
    const int sd = seeds[blk * 64 + g * 16 + l15];
    unsigned roff[5];
    #pragma unroll
    for (int j = 0; j < 5; ++j) {
        int idx = sd + j - 2;
        idx = idx < 0 ? 0 : (idx >= Nrows ? Nrows - 1 : idx);
        roff[j] = (unsigned)idx * (D * 4);
    }
    const char* xb = (const char*)x_rows;
    const bf16x8* W1v = (const bf16x8*)W1f;
    const bf16x8* W2v = (const bf16x8*)W2f;

    // ---- GEMM1: h = x_cat @ W1^T  (M=16 per wave, N=128, K=640)
    f32x4 acc[8] = {};
    #pragma unroll
    for (int ks = 0; ks < KS1; ++ks) {
        const int j = ks >> 2;                              // neighbor (compile-time)
        const float4* p = (const float4*)(xb + roff[j] + (ks & 3) * 128 + lhi * 32);
        float4 p0 = p[0];
        float4 p1 = p[1];
        bf16x8 a;
        a[0] = (short)f32_to_bf16(p0.x); a[1] = (short)f32_to_bf16(p0.y);
        a[2] = (short)f32_to_bf16(p0.z); a[3] = (short)f32_to_bf16(p0.w);
        a[4] = (short)f32_to_bf16(p1.x); a[5] = (short)f32_to_bf16(p1.y);
        a[6] = (short)f32_to_bf16(p1.z); a[7] = (short)f32_to_bf16(p1.w);
        #pragma unroll
        for (int n = 0; n < 8; ++n) {
            bf16x8 b = W1v[(ks * 8 + n) * 64 + l];
            acc[n] = __builtin_amdgcn_mfma_f32_16x16x32_bf16(a, b, acc[n], 0, 0, 0);
        }
    }

    // ---- bias + ReLU -> bf16 h tile in per-wave LDS slice (swizzled)
    unsigned short* H = Hbuf[g];
    #pragma unroll
    for (int n = 0; n < 8; ++n) {
        const int col = n * 16 + l15;
        const float bias = b1[col];
        #pragma unroll
        for (int r = 0; r < 4; ++r) {
            const int row = lhi * 4 + r;   // C/D layout: col=lane&15, row=(lane>>4)*4+reg
            float v = acc[n][r] + bias;
            v = v > 0.f ? v : 0.f;
            H[row * D + (col ^ ((row & 7) << 3))] = f32_to_bf16(v);
        }
    }
    __syncthreads();

    // ---- GEMM2: out = h @ W2^T  (M=16, N=128, K=128)
    f32x4 acc2[8] = {};
    #pragma unroll
    for (int ks = 0; ks < KS2; ++ks) {
        const int row = l15;
        bf16x8 a = *(const bf16x8*)(&H[row * D + ((ks * 32 + lhi * 8) ^ ((row & 7) << 3))]);
        #pragma unroll
        for (int n = 0; n < 8; ++n) {
            bf16x8 b = W2v[(ks * 8 + n) * 64 + l];
            acc2[n] = __builtin_amdgcn_mfma_f32_16x16x32_bf16(a, b, acc2[n], 0, 0, 0);
        }
    }

    // ---- bias + fp32 store
    const size_t rowbase = (size_t)(blk * 64 + g * 16);
    #pragma unroll
    for (int n = 0; n < 8; ++n) {
        const int col = n * 16 + l15;
        const float bias = b2[col];
        #pragma unroll
        for (int r = 0; r < 4; ++r) {
            const int row = lhi * 4 + r;
            out[(rowbase + row) * D + col] = acc2[n][r] + bias;
        }
    }
}

extern "C" void kernel_launch(void* const* d_in, const int* in_sizes, int n_in,
                              void* d_out, int out_size, void* d_ws, size_t ws_size,
                              hipStream_t stream) {
    const float* x_rows = (const float*)d_in[0];
    const int*   seeds  = (const int*)d_in[1];
    const float* W1     = (const float*)d_in[2];
    const float* b1     = (const float*)d_in[3];
    const float* W2     = (const float*)d_in[4];
    const float* b2     = (const float*)d_in[5];
    float* out = (float*)d_out;

    int Nrows = in_sizes[0] / D;
    int B = in_sizes[1];

    unsigned short* W1f = (unsigned short*)d_ws;
    unsigned short* W2f = W1f + W1F_ELEMS;

    prep_frags<<<(W1F_ELEMS + W2F_ELEMS + 255) / 256, 256, 0, stream>>>(W1, W2, W1f, W2f);
    rowmlp_kernel<<<B / 64, 256, 0, stream>>>(x_rows, seeds, W1f, b1, W2f, b2, out, Nrows);
}

// Round 3
// 224.511 us; speedup vs baseline: 1.1155x; 1.1155x over previous
//
#include <hip/hip_runtime.h>
#include <hip/hip_bf16.h>

#define D 128
#define CAT 640
#define BM 32
#define W1F_ELEMS 81920   // 20*8*64*8
#define W2F_ELEMS 16384   // 4*8*64*8

typedef __attribute__((ext_vector_type(8))) short bf16x8;
typedef __attribute__((ext_vector_type(4))) short short4v;
typedef __attribute__((ext_vector_type(4))) float f32x4;

static __device__ __forceinline__ unsigned short f32_to_bf16(float f) {
    unsigned u = __float_as_uint(f);
    unsigned r = u + 0x7FFFu + ((u >> 16) & 1u);   // RNE
    return (unsigned short)(r >> 16);
}

// Pack W1 [128][640] and W2 [128][128] (fp32, torch Linear [out,in]) into MFMA
// B-fragment order: (ks, j16, lane, e) = W[j16*16 + (lane&15)][ks*32 + (lane>>4)*8 + e]
__global__ void prep_frags(const float* __restrict__ W1, const float* __restrict__ W2,
                           unsigned short* __restrict__ W1f, unsigned short* __restrict__ W2f) {
    int f = blockIdx.x * 256 + threadIdx.x;
    if (f < W1F_ELEMS) {
        int e = f & 7, l = (f >> 3) & 63, j16 = (f >> 9) & 7, ks = f >> 12;
        int o = j16 * 16 + (l & 15);
        int k = ks * 32 + ((l >> 4) << 3) + e;
        W1f[f] = f32_to_bf16(W1[o * CAT + k]);
    } else if (f < W1F_ELEMS + W2F_ELEMS) {
        int f2 = f - W1F_ELEMS;
        int e = f2 & 7, l = (f2 >> 3) & 63, j16 = (f2 >> 9) & 7, ks = f2 >> 12;
        int o = j16 * 16 + (l & 15);
        int k = ks * 32 + ((l >> 4) << 3) + e;
        W2f[f2] = f32_to_bf16(W2[o * D + k]);
    }
}

// Block = 256 threads = 4 waves (2x2: wm over 16-row halves, wn over 64-col halves).
// GEMM1 K=640 processed as 5 neighbor-chunks of K=128, software-pipelined:
// stage j+1's 32x128 fp32 rows are gathered->bf16->LDS while chunk j is MFMA'd
// from the other buffer. Load issue is continuous across the kernel body.
__global__ __launch_bounds__(256) void rowmlp_kernel(
    const float* __restrict__ x_rows, const int* __restrict__ seeds,
    const unsigned short* __restrict__ W1f, const float* __restrict__ b1,
    const unsigned short* __restrict__ W2f, const float* __restrict__ b2,
    float* __restrict__ out, int Nrows)
{
    __shared__ __align__(16) unsigned short Ab[2][BM][D];  // 16 KB double buffer
    __shared__ __align__(16) unsigned short Hb[BM][D];     // 8 KB
    __shared__ int sseed[BM];

    const int tid = threadIdx.x;
    const int blk = blockIdx.x;

    if (tid < BM) sseed[tid] = seeds[blk * BM + tid];
    __syncthreads();

    // gather mapping: 8 threads per row, 16 floats (64 B) per thread
    const int grow = tid >> 3;
    const int gcol = (tid & 7) * 16;      // float/short column base
    const float* xb = x_rows;
    const bf16x8* W1v = (const bf16x8*)W1f;
    const bf16x8* W2v = (const bf16x8*)W2f;

    const int l   = tid & 63;
    const int l15 = l & 15;
    const int lhi = l >> 4;
    const int wm  = (tid >> 7) & 1;        // row half
    const int wn  = (tid >> 6) & 1;        // col half
    const int arow = wm * 16 + l15;        // A-fragment row for both GEMMs
    const int aswz = (arow & 7) << 3;

#define STAGE(J, BUF)                                                          \
    {                                                                          \
        int idx = sseed[grow] + (J) - 2;                                       \
        idx = idx < 0 ? 0 : (idx >= Nrows ? Nrows - 1 : idx);                  \
        const float4* src = (const float4*)(xb + (size_t)idx * D + gcol);      \
        float4 v0 = src[0], v1 = src[1], v2 = src[2], v3 = src[3];             \
        unsigned short* dr = Ab[BUF][grow];                                    \
        const int s = (grow & 7) << 3;                                         \
        short4v p;                                                             \
        p[0]=(short)f32_to_bf16(v0.x); p[1]=(short)f32_to_bf16(v0.y);          \
        p[2]=(short)f32_to_bf16(v0.z); p[3]=(short)f32_to_bf16(v0.w);          \
        *(short4v*)(&dr[(gcol + 0) ^ s]) = p;                                  \
        p[0]=(short)f32_to_bf16(v1.x); p[1]=(short)f32_to_bf16(v1.y);          \
        p[2]=(short)f32_to_bf16(v1.z); p[3]=(short)f32_to_bf16(v1.w);          \
        *(short4v*)(&dr[(gcol + 4) ^ s]) = p;                                  \
        p[0]=(short)f32_to_bf16(v2.x); p[1]=(short)f32_to_bf16(v2.y);          \
        p[2]=(short)f32_to_bf16(v2.z); p[3]=(short)f32_to_bf16(v2.w);          \
        *(short4v*)(&dr[(gcol + 8) ^ s]) = p;                                  \
        p[0]=(short)f32_to_bf16(v3.x); p[1]=(short)f32_to_bf16(v3.y);          \
        p[2]=(short)f32_to_bf16(v3.z); p[3]=(short)f32_to_bf16(v3.w);          \
        *(short4v*)(&dr[(gcol + 12) ^ s]) = p;                                 \
    }

    f32x4 acc[4] = {};

    STAGE(0, 0)
    __syncthreads();

    #pragma unroll
    for (int j = 0; j < 5; ++j) {
        const int cur = j & 1;
        if (j < 4) STAGE(j + 1, cur ^ 1)
        #pragma unroll
        for (int ks = 0; ks < 4; ++ks) {
            bf16x8 a = *(const bf16x8*)(&Ab[cur][arow][(ks * 32 + lhi * 8) ^ aswz]);
            #pragma unroll
            for (int n = 0; n < 4; ++n) {
                const int j16 = wn * 4 + n;
                bf16x8 b = W1v[((j * 4 + ks) * 8 + j16) * 64 + l];
                acc[n] = __builtin_amdgcn_mfma_f32_16x16x32_bf16(a, b, acc[n], 0, 0, 0);
            }
        }
        __syncthreads();
    }

    // bias + ReLU -> bf16 h tile (swizzled like Ab)
    #pragma unroll
    for (int n = 0; n < 4; ++n) {
        const int col = wn * 64 + n * 16 + l15;
        const float bias = b1[col];
        #pragma unroll
        for (int r = 0; r < 4; ++r) {
            const int row = wm * 16 + lhi * 4 + r;  // C/D: col=lane&15, row=(lane>>4)*4+reg
            float v = acc[n][r] + bias;
            v = v > 0.f ? v : 0.f;
            Hb[row][col ^ ((row & 7) << 3)] = f32_to_bf16(v);
        }
        acc[n] = (f32x4){0.f, 0.f, 0.f, 0.f};
    }
    __syncthreads();

    // GEMM2: out = h @ W2^T  (per wave M=16, N=64, K=128)
    #pragma unroll
    for (int ks = 0; ks < 4; ++ks) {
        bf16x8 a = *(const bf16x8*)(&Hb[arow][(ks * 32 + lhi * 8) ^ aswz]);
        #pragma unroll
        for (int n = 0; n < 4; ++n) {
            const int j16 = wn * 4 + n;
            bf16x8 b = W2v[(ks * 8 + j16) * 64 + l];
            acc[n] = __builtin_amdgcn_mfma_f32_16x16x32_bf16(a, b, acc[n], 0, 0, 0);
        }
    }

    // bias + fp32 store
    #pragma unroll
    for (int n = 0; n < 4; ++n) {
        const int col = wn * 64 + n * 16 + l15;
        const float bias = b2[col];
        #pragma unroll
        for (int r = 0; r < 4; ++r) {
            const int row = wm * 16 + lhi * 4 + r;
            out[(size_t)(blk * BM + row) * D + col] = acc[n][r] + bias;
        }
    }
#undef STAGE
}

extern "C" void kernel_launch(void* const* d_in, const int* in_sizes, int n_in,
                              void* d_out, int out_size, void* d_ws, size_t ws_size,
                              hipStream_t stream) {
    const float* x_rows = (const float*)d_in[0];
    const int*   seeds  = (const int*)d_in[1];
    const float* W1     = (const float*)d_in[2];
    const float* b1     = (const float*)d_in[3];
    const float* W2     = (const float*)d_in[4];
    const float* b2     = (const float*)d_in[5];
    float* out = (float*)d_out;

    int Nrows = in_sizes[0] / D;
    int B = in_sizes[1];

    unsigned short* W1f = (unsigned short*)d_ws;
    unsigned short* W2f = W1f + W1F_ELEMS;

    prep_frags<<<(W1F_ELEMS + W2F_ELEMS + 255) / 256, 256, 0, stream>>>(W1, W2, W1f, W2f);
    rowmlp_kernel<<<B / BM, 256, 0, stream>>>(x_rows, seeds, W1f, b1, W2f, b2, out, Nrows);
}

// Round 4
// 212.985 us; speedup vs baseline: 1.1759x; 1.0541x over previous
//
#include <hip/hip_runtime.h>
#include <hip/hip_bf16.h>

#define D 128
#define CAT 640
#define BM 32
#define W1F_ELEMS 81920   // 20*8*64*8
#define W2F_ELEMS 16384   // 4*8*64*8

typedef __attribute__((ext_vector_type(8))) short bf16x8;
typedef __attribute__((ext_vector_type(4))) short short4v;
typedef __attribute__((ext_vector_type(4))) float f32x4;

static __device__ __forceinline__ unsigned short f32_to_bf16(float f) {
    unsigned u = __float_as_uint(f);
    unsigned r = u + 0x7FFFu + ((u >> 16) & 1u);   // RNE
    return (unsigned short)(r >> 16);
}

// Pack W1 [128][640] and W2 [128][128] (fp32, torch Linear [out,in]) into MFMA
// B-fragment order: (ks, j16, lane, e) = W[j16*16 + (lane&15)][ks*32 + (lane>>4)*8 + e]
__global__ void prep_frags(const float* __restrict__ W1, const float* __restrict__ W2,
                           unsigned short* __restrict__ W1f, unsigned short* __restrict__ W2f) {
    int f = blockIdx.x * 256 + threadIdx.x;
    if (f < W1F_ELEMS) {
        int e = f & 7, l = (f >> 3) & 63, j16 = (f >> 9) & 7, ks = f >> 12;
        int o = j16 * 16 + (l & 15);
        int k = ks * 32 + ((l >> 4) << 3) + e;
        W1f[f] = f32_to_bf16(W1[o * CAT + k]);
    } else if (f < W1F_ELEMS + W2F_ELEMS) {
        int f2 = f - W1F_ELEMS;
        int e = f2 & 7, l = (f2 >> 3) & 63, j16 = (f2 >> 9) & 7, ks = f2 >> 12;
        int o = j16 * 16 + (l & 15);
        int k = ks * 32 + ((l >> 4) << 3) + e;
        W2f[f2] = f32_to_bf16(W2[o * D + k]);
    }
}

// R4: R1's winning structure (bulk decoupled gather -> LDS -> GEMM1 -> GEMM2)
// but 512 threads/block at the same BM=32 / 48KB LDS, so the same LDS
// allocation hosts 2x the waves: 3 blocks/CU = 24 waves/CU (vs R1's 12).
// __launch_bounds__(512,6) caps VGPR ~85 so 3 blocks are realizable.
// 8 waves = 2 row-halves (wm) x 4 col-groups (wn); each wave: 16 rows x 32 cols.
__global__ __launch_bounds__(512, 6) void rowmlp_kernel(
    const float* __restrict__ x_rows, const int* __restrict__ seeds,
    const unsigned short* __restrict__ W1f, const float* __restrict__ b1,
    const unsigned short* __restrict__ W2f, const float* __restrict__ b2,
    float* __restrict__ out, int Nrows)
{
    __shared__ __align__(16) unsigned short Ab[BM][CAT];  // 40 KB, XOR-swizzled
    __shared__ __align__(16) unsigned short Hb[BM][D];    // 8 KB, XOR-swizzled
    __shared__ int sseed[BM];

    const int tid = threadIdx.x;
    const int blk = blockIdx.x;

    if (tid < BM) sseed[tid] = seeds[blk * BM + tid];
    __syncthreads();

    // ---- bulk decoupled gather: 160 segments of 512 B; 16 segments/iter,
    // 10 independent float4 loads per thread, no barriers until the end.
    {
        const int lane32 = tid & 31;
        const int segbase = tid >> 5;          // 0..15
        #pragma unroll
        for (int it = 0; it < 10; ++it) {
            int seg = it * 16 + segbase;       // 0..159
            int row = seg / 5;
            int j = seg - row * 5;
            int idx = sseed[row] + j - 2;
            idx = idx < 0 ? 0 : (idx >= Nrows ? Nrows - 1 : idx);
            float4 v = *((const float4*)(x_rows + (size_t)idx * D) + lane32);
            short4v p;
            p[0] = (short)f32_to_bf16(v.x); p[1] = (short)f32_to_bf16(v.y);
            p[2] = (short)f32_to_bf16(v.z); p[3] = (short)f32_to_bf16(v.w);
            int kshort = j * D + lane32 * 4;
            *(short4v*)(&Ab[row][kshort ^ ((row & 7) << 3)]) = p;
        }
    }
    __syncthreads();

    const int wave = tid >> 6;
    const int wm   = wave >> 2;            // row half (0/1)
    const int wn   = wave & 3;             // col quarter (0..3)
    const int l    = tid & 63;
    const int l15  = l & 15;
    const int lhi  = l >> 4;
    const int arow = wm * 16 + l15;
    const int aswz = (arow & 7) << 3;

    const bf16x8* W1v = (const bf16x8*)W1f;
    const bf16x8* W2v = (const bf16x8*)W2f;

    // ---- GEMM1: h = x_cat @ W1^T  (per wave: M=16, N=32, K=640)
    f32x4 acc[2] = {};
    #pragma unroll
    for (int ks = 0; ks < 20; ++ks) {
        bf16x8 a = *(const bf16x8*)(&Ab[arow][(ks * 32 + lhi * 8) ^ aswz]);
        #pragma unroll
        for (int n = 0; n < 2; ++n) {
            const int j16 = wn * 2 + n;
            bf16x8 b = W1v[(ks * 8 + j16) * 64 + l];
            acc[n] = __builtin_amdgcn_mfma_f32_16x16x32_bf16(a, b, acc[n], 0, 0, 0);
        }
    }

    // ---- bias + ReLU -> bf16 h tile (swizzled)
    #pragma unroll
    for (int n = 0; n < 2; ++n) {
        const int col = wn * 32 + n * 16 + l15;
        const float bias = b1[col];
        #pragma unroll
        for (int r = 0; r < 4; ++r) {
            const int row = wm * 16 + lhi * 4 + r;  // C/D: col=lane&15, row=(lane>>4)*4+reg
            float v = acc[n][r] + bias;
            v = v > 0.f ? v : 0.f;
            Hb[row][col ^ ((row & 7) << 3)] = f32_to_bf16(v);
        }
        acc[n] = (f32x4){0.f, 0.f, 0.f, 0.f};
    }
    __syncthreads();

    // ---- GEMM2: out = h @ W2^T  (per wave: M=16, N=32, K=128)
    #pragma unroll
    for (int ks = 0; ks < 4; ++ks) {
        bf16x8 a = *(const bf16x8*)(&Hb[arow][(ks * 32 + lhi * 8) ^ aswz]);
        #pragma unroll
        for (int n = 0; n < 2; ++n) {
            const int j16 = wn * 2 + n;
            bf16x8 b = W2v[(ks * 8 + j16) * 64 + l];
            acc[n] = __builtin_amdgcn_mfma_f32_16x16x32_bf16(a, b, acc[n], 0, 0, 0);
        }
    }

    // ---- bias + fp32 store
    #pragma unroll
    for (int n = 0; n < 2; ++n) {
        const int col = wn * 32 + n * 16 + l15;
        const float bias = b2[col];
        #pragma unroll
        for (int r = 0; r < 4; ++r) {
            const int row = wm * 16 + lhi * 4 + r;
            out[(size_t)(blk * BM + row) * D + col] = acc[n][r] + bias;
        }
    }
}

extern "C" void kernel_launch(void* const* d_in, const int* in_sizes, int n_in,
                              void* d_out, int out_size, void* d_ws, size_t ws_size,
                              hipStream_t stream) {
    const float* x_rows = (const float*)d_in[0];
    const int*   seeds  = (const int*)d_in[1];
    const float* W1     = (const float*)d_in[2];
    const float* b1     = (const float*)d_in[3];
    const float* W2     = (const float*)d_in[4];
    const float* b2     = (const float*)d_in[5];
    float* out = (float*)d_out;

    int Nrows = in_sizes[0] / D;
    int B = in_sizes[1];

    unsigned short* W1f = (unsigned short*)d_ws;
    unsigned short* W2f = W1f + W1F_ELEMS;

    prep_frags<<<(W1F_ELEMS + W2F_ELEMS + 255) / 256, 256, 0, stream>>>(W1, W2, W1f, W2f);
    rowmlp_kernel<<<B / BM, 512, 0, stream>>>(x_rows, seeds, W1f, b1, W2f, b2, out, Nrows);
}